// Round 9
// baseline (219.883 us; speedup 1.0000x reference)
//
#include <hip/hip_runtime.h>

typedef __attribute__((ext_vector_type(8))) short short8;
typedef __attribute__((ext_vector_type(4))) float floatx4;
typedef __attribute__((ext_vector_type(4))) unsigned short ushort4v;

__device__ __forceinline__ unsigned short f2bf(float f) {
  unsigned int u = __float_as_uint(f);
  u += 0x7FFFu + ((u >> 16) & 1u);           // round-to-nearest-even
  return (unsigned short)(u >> 16);
}

__device__ __forceinline__ unsigned int cvt_pk_bf16(float lo, float hi) {
  unsigned int r;
  asm("v_cvt_pk_bf16_f32 %0, %1, %2" : "=v"(r) : "v"(lo), "v"(hi));
  return r;
}

__device__ __forceinline__ void async_copy16(const void* g, void* l) {
  __builtin_amdgcn_global_load_lds(
      (const __attribute__((address_space(1))) unsigned int*)g,
      (__attribute__((address_space(3))) unsigned int*)l, 16, 0, 0);
}

__device__ __forceinline__ float fexp2(float x) {
#if __has_builtin(__builtin_amdgcn_exp2f)
  return __builtin_amdgcn_exp2f(x);
#else
  return exp2f(x);
#endif
}

// ---------------------------------------------------------------- convert (fused)
// ranges (in float4 units): x 2097152 | w_qkv 786432 | w_out 262144
__global__ __launch_bounds__(256) void cvt_all(const float* __restrict__ x,
                                               const float* __restrict__ wq,
                                               const float* __restrict__ wo,
                                               unsigned short* __restrict__ Xb,
                                               unsigned short* __restrict__ Wqb,
                                               unsigned short* __restrict__ Wob) {
  int i = blockIdx.x * blockDim.x + threadIdx.x;
  const float* src;
  unsigned short* dst;
  int off;
  if (i < 2097152) { src = x;  dst = Xb;  off = i; }
  else if (i < 2883584) { src = wq; dst = Wqb; off = i - 2097152; }
  else { src = wo; dst = Wob; off = i - 2883584; }
  float4 v = reinterpret_cast<const float4*>(src)[off];
  ushort4v o;
  o[0] = f2bf(v.x); o[1] = f2bf(v.y); o[2] = f2bf(v.z); o[3] = f2bf(v.w);
  reinterpret_cast<ushort4v*>(dst)[off] = o;
}

// ---------------------------------------------------------------- GEMM NT
// C(M,N) = A(M,K) * B(N,K)^T + bias.  MODE 0: fp32 C out. MODE 1: QKV scatter.
// m97-exact recipe: BK=32, single 16KB LDS, 128x128 tile, 4 waves (2x2),
// wave-tile 64x64 (16 MFMA : 8 ds_read_b128 per K-step). Residency (4
// blocks/CU: VGPR ~115 -> 4 waves/SIMD; LDS allows 10) hides the per-step
// drain (m114). Source-side XOR swizzle (4 chunks/row): source c=(t&3)^(r&3),
// read chunk lh^(lr&3) -> composes to linear k-order in registers; residual
// 4-way read alias costs 1.58x (m136), the regime m97 tolerated at 874 TF.
// XCD-chunked 1D grid (bid&7 = xcd owns contiguous m-slice).
template <int MODE, int NX>
__global__ __launch_bounds__(256) void gemm_nt(const unsigned short* __restrict__ A,
                                               const unsigned short* __restrict__ B,
                                               const float* __restrict__ bias,
                                               void* __restrict__ C,
                                               int M, int N, int K) {
  __shared__ __align__(16) unsigned short lA[128 * 32];
  __shared__ __align__(16) unsigned short lB[128 * 32];
  const int tid = threadIdx.x;
  const int lane = tid & 63, wave = tid >> 6;
  const int lr = lane & 15, lh = lane >> 4;
  const int chunk = gridDim.x >> 3;
  const int g2 = (blockIdx.x & 7) * chunk + (blockIdx.x >> 3);
  const int m0 = (g2 / NX) * 128, n0 = (g2 % NX) * 128;
  const int wm = (wave >> 1) * 64, wn = (wave & 1) * 64;
  floatx4 acc[4][4] = {};

  const int rdc = (lh ^ (lr & 3)) * 8;   // swizzled read chunk (elems)

  for (int k0 = 0; k0 < K; k0 += 32) {
    __syncthreads();   // all waves done reading previous tile
    // stage 16KB: 2 issues each for A,B; source chunk c=(t&3)^(r&3), LDS linear
#pragma unroll
    for (int c0 = 0; c0 < 512; c0 += 256) {
      int L = c0 + tid;
      int r = L >> 2;
      int c = (L & 3) ^ (r & 3);
      async_copy16(A + (size_t)(m0 + r) * K + k0 + c * 8, &lA[(size_t)(c0 + wave * 64) * 8]);
      async_copy16(B + (size_t)(n0 + r) * K + k0 + c * 8, &lB[(size_t)(c0 + wave * 64) * 8]);
    }
    __syncthreads();   // tile resident
    short8 af[4], bfr[4];
#pragma unroll
    for (int mf = 0; mf < 4; ++mf)
      af[mf] = *(const short8*)&lA[(wm + mf * 16 + lr) * 32 + rdc];
#pragma unroll
    for (int nf = 0; nf < 4; ++nf)
      bfr[nf] = *(const short8*)&lB[(wn + nf * 16 + lr) * 32 + rdc];
#pragma unroll
    for (int mf = 0; mf < 4; ++mf)
#pragma unroll
      for (int nf = 0; nf < 4; ++nf)
        acc[mf][nf] = __builtin_amdgcn_mfma_f32_16x16x32_bf16(af[mf], bfr[nf], acc[mf][nf], 0, 0, 0);
  }

#pragma unroll
  for (int mf = 0; mf < 4; ++mf)
#pragma unroll
    for (int nf = 0; nf < 4; ++nf)
#pragma unroll
      for (int r = 0; r < 4; ++r) {
        int row = m0 + wm + mf * 16 + lh * 4 + r;   // C row (m)
        int col = n0 + wn + nf * 16 + lr;           // C col (n)
        float v = acc[mf][nf][r] + bias[col];
        if (MODE == 0) {
          ((float*)C)[(size_t)row * N + col] = v;
        } else {
          // row = s*4+b ; col = part*1024 + h*64 + d ; head g = b*16+h
          int part = col >> 10, wi = col & 1023;
          int h = wi >> 6, dd = wi & 63;
          int s = row >> 2, b = row & 3;
          int gg = b * 16 + h;
          size_t base = (size_t)part * (64u * 2048u * 64u);
          if (part == 0) {
            // fold 1/sqrt(d_k) * log2(e) into Q (softmax runs in log2 domain)
            v *= 0.18033688011112042f;
            ((unsigned short*)C)[base + ((size_t)gg * 2048 + s) * 64 + dd] = f2bf(v);
          } else if (part == 1) {
            ((unsigned short*)C)[base + ((size_t)gg * 2048 + s) * 64 + dd] = f2bf(v);
          } else {
            // V stored TRANSPOSED per head: Vt[g][d][s]
            ((unsigned short*)C)[base + ((size_t)gg * 64 + dd) * 2048 + s] = f2bf(v);
          }
        }
      }
}

// ---------------------------------------------------------------- attention
// 1024 blocks (XCD-swizzled: one XCD owns 8 heads x 16 q-tiles; qt remapped so
// every CU's 4 blocks total exactly 68 KV tiles under causal).
// 4 waves x 32 q-rows, KV tile = 64, double-buffered pipelined staging.
// Swapped QK^T: S^T = mfma(K, Q) so each lane owns 16 S-values of ONE q-row.
__global__ __launch_bounds__(256, 3) void attn_fwd(const unsigned short* __restrict__ Qb,
                                                   const unsigned short* __restrict__ Kb,
                                                   const unsigned short* __restrict__ Vt,
                                                   unsigned short* __restrict__ Att,
                                                   const int* __restrict__ causal_p) {
  __shared__ __align__(16) unsigned short lK[2][64 * 64];
  __shared__ __align__(16) unsigned short lV[2][64 * 64];   // Vt tile: rows=d, cols=kv
  __shared__ __align__(16) unsigned short lP[4][32 * 64];   // per-wave P, XOR-swizzled
  const int tid = threadIdx.x;
  const int lane = tid & 63, w = tid >> 6;
  const int lr = lane & 15, lh = lane >> 4;
  const int bid = blockIdx.x;
  const int g = (bid & 7) + 8 * (bid >> 7);
  int qt = (bid >> 3) & 15;
  qt = (qt & 12) | ((qt ^ (qt >> 2)) & 3);    // per-CU causal load balance (bijective)
  const int q0 = qt * 128;
  const int causal = causal_p[0];
  const size_t headOff = (size_t)g * 2048 * 64;
  const size_t vtHead = (size_t)g * 64 * 2048;
  const int q0w = q0 + w * 32;

  short8 qf[2][2];
#pragma unroll
  for (int qb = 0; qb < 2; ++qb)
#pragma unroll
    for (int kf = 0; kf < 2; ++kf)
      qf[qb][kf] = *(const short8*)&Qb[headOff + (size_t)(q0w + qb * 16 + lr) * 64 + kf * 32 + lh * 8];

  floatx4 oacc[2][4] = {};
  float mrow[2] = {-1e30f, -1e30f}, lrow[2] = {0.f, 0.f};

  const int nt = causal ? (q0 + 128) / 64 : 2048 / 64;
  const int qmax_w = q0w + 31;

  // staging: source-side XOR swizzle (chunk c ^= row&7), linear LDS dest.
  auto stageK = [&](int buf, int kv0) {
#pragma unroll
    for (int c0 = 0; c0 < 512; c0 += 256) {
      int L = c0 + tid;
      int kvr = L >> 3;
      int c = (tid & 7) ^ (kvr & 7);
      async_copy16(Kb + headOff + (size_t)(kv0 + kvr) * 64 + c * 8,
                   &lK[buf][(size_t)(c0 + w * 64) * 8]);
    }
  };
  auto stageV = [&](int buf, int kv0) {
#pragma unroll
    for (int c0 = 0; c0 < 512; c0 += 256) {
      int L = c0 + tid;
      int dr = L >> 3;
      int c = (tid & 7) ^ (dr & 7);
      async_copy16(Vt + vtHead + (size_t)dr * 2048 + kv0 + c * 8,
                   &lV[buf][(size_t)(c0 + w * 64) * 8]);
    }
  };

  stageK(0, 0);
  stageV(0, 0);
  int cur = 0;

  for (int t = 0; t < nt; ++t) {
    const int kv0 = t * 64;
    if (t + 1 < nt) {
      stageK(cur ^ 1, kv0 + 64);
      stageV(cur ^ 1, kv0 + 64);
      asm volatile("s_waitcnt vmcnt(4)" ::: "memory");  // tile t's 4 loads done
    } else {
      asm volatile("s_waitcnt vmcnt(0)" ::: "memory");
    }
    __builtin_amdgcn_s_barrier();
    asm volatile("" ::: "memory");

    if (!causal || kv0 <= qmax_w) {
      // ---- S^T = K * Q^T : sacc[qb][nf][r] = S[q = q0w+qb*16+lr][kv = kv0+nf*16+lh*4+r]
      floatx4 sacc[2][4] = {};
      __builtin_amdgcn_s_setprio(1);
#pragma unroll
      for (int kk = 0; kk < 2; ++kk) {
        short8 kfr[4];
#pragma unroll
        for (int nf = 0; nf < 4; ++nf)
          kfr[nf] = *(const short8*)&lK[cur][(nf * 16 + lr) * 64 + (((kk * 4 + lh) ^ (lr & 7)) * 8)];
#pragma unroll
        for (int qb = 0; qb < 2; ++qb)
#pragma unroll
          for (int nf = 0; nf < 4; ++nf)
            sacc[qb][nf] = __builtin_amdgcn_mfma_f32_16x16x32_bf16(kfr[nf], qf[qb][kk], sacc[qb][nf], 0, 0, 0);
      }
      __builtin_amdgcn_s_setprio(0);

      if (causal && kv0 + 63 > q0w) {
#pragma unroll
        for (int qb = 0; qb < 2; ++qb) {
          int q = q0w + qb * 16 + lr;
#pragma unroll
          for (int nf = 0; nf < 4; ++nf)
#pragma unroll
            for (int r = 0; r < 4; ++r) {
              int kv = kv0 + nf * 16 + lh * 4 + r;
              if (kv > q) sacc[qb][nf][r] = -1e30f;
            }
        }
      }

      // ---- online softmax: stats lane-local per q (lanes sharing lr share q)
      float alpha[2];
#pragma unroll
      for (int qb = 0; qb < 2; ++qb) {
        float rm = -1e30f;
#pragma unroll
        for (int nf = 0; nf < 4; ++nf)
          rm = fmaxf(rm, fmaxf(fmaxf(sacc[qb][nf][0], sacc[qb][nf][1]),
                               fmaxf(sacc[qb][nf][2], sacc[qb][nf][3])));
        rm = fmaxf(rm, __shfl_xor(rm, 16, 64));
        rm = fmaxf(rm, __shfl_xor(rm, 32, 64));
        float mn = fmaxf(mrow[qb], rm);
        alpha[qb] = fexp2(mrow[qb] - mn);
        mrow[qb] = mn;
        float rs = 0.f;
#pragma unroll
        for (int nf = 0; nf < 4; ++nf)
#pragma unroll
          for (int r = 0; r < 4; ++r) {
            float p = fexp2(sacc[qb][nf][r] - mn);
            sacc[qb][nf][r] = p;
            rs += p;
          }
        rs += __shfl_xor(rs, 16, 64);
        rs += __shfl_xor(rs, 32, 64);
        lrow[qb] = lrow[qb] * alpha[qb] + rs;
      }

      // ---- P -> LDS: pack 4 contiguous kv per lane, XOR-swizzled, ds_write_b64
#pragma unroll
      for (int qb = 0; qb < 2; ++qb)
#pragma unroll
        for (int nf = 0; nf < 4; ++nf) {
          uint2 pk;
          pk.x = cvt_pk_bf16(sacc[qb][nf][0], sacc[qb][nf][1]);
          pk.y = cvt_pk_bf16(sacc[qb][nf][2], sacc[qb][nf][3]);
          int c = (2 * nf + (lh >> 1)) ^ (lr & 7);
          *(uint2*)&lP[w][(qb * 16 + lr) * 64 + c * 8 + (lh & 1) * 4] = pk;
        }

      // ---- rescale O with alpha transposed to the accumulator row domain
#pragma unroll
      for (int qb = 0; qb < 2; ++qb) {
        float at[4];
#pragma unroll
        for (int r = 0; r < 4; ++r)
          at[r] = __shfl(alpha[qb], lh * 4 + r, 64);
#pragma unroll
        for (int nd = 0; nd < 4; ++nd)
#pragma unroll
          for (int r = 0; r < 4; ++r)
            oacc[qb][nd][r] *= at[r];
      }

      // ---- PV: O += P * Vt^T
      __builtin_amdgcn_s_setprio(1);
#pragma unroll
      for (int kk = 0; kk < 2; ++kk) {
        short8 pf[2], vf[4];
#pragma unroll
        for (int qb = 0; qb < 2; ++qb)
          pf[qb] = *(const short8*)&lP[w][(qb * 16 + lr) * 64 + (((kk * 4 + lh) ^ (lr & 7)) * 8)];
#pragma unroll
        for (int nd = 0; nd < 4; ++nd)
          vf[nd] = *(const short8*)&lV[cur][(nd * 16 + lr) * 64 + (((kk * 4 + lh) ^ (lr & 7)) * 8)];
#pragma unroll
        for (int qb = 0; qb < 2; ++qb)
#pragma unroll
          for (int nd = 0; nd < 4; ++nd)
            oacc[qb][nd] = __builtin_amdgcn_mfma_f32_16x16x32_bf16(pf[qb], vf[nd], oacc[qb][nd], 0, 0, 0);
      }
      __builtin_amdgcn_s_setprio(0);
    }
    asm volatile("" ::: "memory");
    __builtin_amdgcn_s_barrier();   // everyone done reading buf[cur] before overwrite
    cur ^= 1;
  }

  const int bb = g >> 4, hh = g & 15;
#pragma unroll
  for (int qb = 0; qb < 2; ++qb) {
    float invl = 1.f / lrow[qb];
    float it[4];
#pragma unroll
    for (int r = 0; r < 4; ++r)
      it[r] = __shfl(invl, lh * 4 + r, 64);
#pragma unroll
    for (int r = 0; r < 4; ++r) {
      int s = q0w + qb * 16 + lh * 4 + r;
#pragma unroll
      for (int nd = 0; nd < 4; ++nd) {
        int dd = nd * 16 + lr;
        Att[((size_t)s * 4 + bb) * 1024 + hh * 64 + dd] = f2bf(oacc[qb][nd][r] * it[r]);
      }
    }
  }
}

// ---------------------------------------------------------------- launcher
extern "C" void kernel_launch(void* const* d_in, const int* in_sizes, int n_in,
                              void* d_out, int out_size, void* d_ws, size_t ws_size,
                              hipStream_t stream) {
  const float* x     = (const float*)d_in[0];
  const float* w_qkv = (const float*)d_in[1];
  const float* b_qkv = (const float*)d_in[2];
  const float* w_out = (const float*)d_in[3];
  const float* b_out = (const float*)d_in[4];
  const int*   causal = (const int*)d_in[5];
  float* out = (float*)d_out;

  char* ws = (char*)d_ws;
  size_t off = 0;
  auto alloc = [&](size_t bytes) { char* p = ws + off; off += (bytes + 255) & ~(size_t)255; return p; };
  unsigned short* Xbf  = (unsigned short*)alloc((size_t)8192 * 1024 * 2);
  unsigned short* Wqkv = (unsigned short*)alloc((size_t)3072 * 1024 * 2);
  unsigned short* Wout = (unsigned short*)alloc((size_t)1024 * 1024 * 2);
  unsigned short* QKV  = (unsigned short*)alloc((size_t)3 * 64 * 2048 * 64 * 2);
  unsigned short* Att  = (unsigned short*)alloc((size_t)8192 * 1024 * 2);
  (void)ws_size; (void)in_sizes; (void)n_in; (void)out_size;

  cvt_all<<<12288, 256, 0, stream>>>(x, w_qkv, w_out, Xbf, Wqkv, Wout);

  // 1D grids, XCD-chunked decode inside; nwg divisible by 8
  gemm_nt<1, 24><<<24 * 64, 256, 0, stream>>>(Xbf, Wqkv, b_qkv, (void*)QKV, 8192, 3072, 1024);

  const unsigned short* Qh = QKV;
  const unsigned short* Kh = QKV + (size_t)64 * 2048 * 64;
  const unsigned short* Vh = QKV + (size_t)2 * 64 * 2048 * 64;
  attn_fwd<<<1024, 256, 0, stream>>>(Qh, Kh, Vh, Att, causal);

  gemm_nt<0, 8><<<8 * 64, 256, 0, stream>>>(Att, Wout, b_out, (void*)out, 8192, 1024, 1024);
}

// Round 10
// 218.669 us; speedup vs baseline: 1.0056x; 1.0056x over previous
//
#include <hip/hip_runtime.h>

typedef __attribute__((ext_vector_type(8))) short short8;
typedef __attribute__((ext_vector_type(4))) float floatx4;
typedef __attribute__((ext_vector_type(4))) unsigned short ushort4v;

__device__ __forceinline__ unsigned short f2bf(float f) {
  unsigned int u = __float_as_uint(f);
  u += 0x7FFFu + ((u >> 16) & 1u);           // round-to-nearest-even
  return (unsigned short)(u >> 16);
}

__device__ __forceinline__ unsigned int cvt_pk_bf16(float lo, float hi) {
  unsigned int r;
  asm("v_cvt_pk_bf16_f32 %0, %1, %2" : "=v"(r) : "v"(lo), "v"(hi));
  return r;
}

__device__ __forceinline__ void async_copy16(const void* g, void* l) {
  __builtin_amdgcn_global_load_lds(
      (const __attribute__((address_space(1))) unsigned int*)g,
      (__attribute__((address_space(3))) unsigned int*)l, 16, 0, 0);
}

__device__ __forceinline__ float fexp2(float x) {
#if __has_builtin(__builtin_amdgcn_exp2f)
  return __builtin_amdgcn_exp2f(x);
#else
  return exp2f(x);
#endif
}

// ---------------------------------------------------------------- convert (fused)
__global__ __launch_bounds__(256) void cvt_all(const float* __restrict__ x,
                                               const float* __restrict__ wq,
                                               const float* __restrict__ wo,
                                               unsigned short* __restrict__ Xb,
                                               unsigned short* __restrict__ Wqb,
                                               unsigned short* __restrict__ Wob) {
  int i = blockIdx.x * blockDim.x + threadIdx.x;
  const float* src;
  unsigned short* dst;
  int off;
  if (i < 2097152) { src = x;  dst = Xb;  off = i; }
  else if (i < 2883584) { src = wq; dst = Wqb; off = i - 2097152; }
  else { src = wo; dst = Wob; off = i - 2883584; }
  float4 v = reinterpret_cast<const float4*>(src)[off];
  ushort4v o;
  o[0] = f2bf(v.x); o[1] = f2bf(v.y); o[2] = f2bf(v.z); o[3] = f2bf(v.w);
  reinterpret_cast<ushort4v*>(dst)[off] = o;
}

// ---------------------------------------------------------------- epilogue scatter
__device__ __forceinline__ void store_c(int MODE, void* C, int N, int row, int col, float v) {
  if (MODE == 0) {
    ((float*)C)[(size_t)row * N + col] = v;
  } else {
    // row = s*4+b ; col = part*1024 + h*64 + d ; head g = b*16+h
    int part = col >> 10, wi = col & 1023;
    int h = wi >> 6, dd = wi & 63;
    int s = row >> 2, b = row & 3;
    int gg = b * 16 + h;
    size_t base = (size_t)part * (64u * 2048u * 64u);
    if (part == 0) {
      v *= 0.18033688011112042f;   // fold 1/sqrt(d_k)*log2(e) into Q
      ((unsigned short*)C)[base + ((size_t)gg * 2048 + s) * 64 + dd] = f2bf(v);
    } else if (part == 1) {
      ((unsigned short*)C)[base + ((size_t)gg * 2048 + s) * 64 + dd] = f2bf(v);
    } else {
      ((unsigned short*)C)[base + ((size_t)gg * 64 + dd) * 2048 + s] = f2bf(v);  // Vt[g][d][s]
    }
  }
}

// ---------------------------------------------------------------- GEMM 256x256 8-phase
// Faithful m201-style port. BM=BN=256, BK=64, 8 waves (2M x 4N), per-wave
// 128x64, acc 128 VGPR. LDS 128 KB: lA/lB [2 buf][256 rows][64], halves =
// 128-row blocks. Per iter: 2 K-tiles (even->buf0, odd->buf1), 8 phases.
// Quadrant order per tile: Q1(a-lo,b-lo) Q3(b-hi) Q2(a-hi) Q4(-) so b stays
// reg-resident (live ~192 VGPR).
// Stage schedule (halves of tiles 2j+2 'e'->buf0, 2j+3 'o'->buf1):
//   ph2: Bh0e  ph3: Ah0e  ph4: Bh1e  ph5: Ah1e  ph6: Bh0o+Bh1o  ph7: Ah0o+Ah1o
// WAR ledger (2 barriers/phase; stage at phase-top, >=1 phase after region's
// last read): B-h0/h1 buf0 last read ph1 -> staged ph2/ph4; A halves buf0 last
// read ph2 -> ph3/ph5; B buf1 last read ph5 -> ph6; A buf1 last read ph6 -> ph7.
// RAW ledger (counted waits, never drain in steady state):
//   end-ph3 vmcnt(4): newer = ph2+ph3 stages (4 loads) -> tile 2j+1 landed.
//   end-ph7 vmcnt(8): newer = ph6+ph7 stages (8 loads) -> tile 2j+2 landed.
//   last iter (no staging): end-ph3 vmcnt(0).
template <int MODE, int NX>
__global__ __launch_bounds__(512) void gemm256_8p(const unsigned short* __restrict__ A,
                                                  const unsigned short* __restrict__ B,
                                                  const float* __restrict__ bias,
                                                  void* __restrict__ C,
                                                  int M, int N, int K) {
  __shared__ __align__(16) unsigned short lA[2][256 * 64];
  __shared__ __align__(16) unsigned short lB[2][256 * 64];
  const int tid = threadIdx.x;                 // 0..511
  const int lane = tid & 63, wave = tid >> 6;  // 8 waves
  const int lr = lane & 15, lh = lane >> 4;
  const int chunkg = gridDim.x >> 3;           // XCD-chunked 1D grid
  const int g2 = (blockIdx.x & 7) * chunkg + (blockIdx.x >> 3);
  const int m0 = (g2 / NX) * 256, n0 = (g2 % NX) * 256;
  const int wr = wave >> 2, wc = wave & 3;     // 2(M) x 4(N)
  floatx4 acc[8][4] = {};

  // stage one 128x64 half (2 x gload_lds/thread); source chunk XOR-swizzled
  auto stageHalf = [&](const unsigned short* __restrict__ S, int srow0,
                       unsigned short* lds, int k0) {
#pragma unroll
    for (int c0 = 0; c0 < 1024; c0 += 512) {
      int L = c0 + tid;
      int r = L >> 3;
      int c = (L & 7) ^ (r & 7);
      async_copy16(S + (size_t)(srow0 + r) * K + k0 + c * 8,
                   lds + (size_t)(c0 + wave * 64) * 8);
    }
  };

  short8 a[4][2], bl[2][2], bh[2][2];

  auto rdA = [&](int buf, int rowoff) {
#pragma unroll
    for (int fr = 0; fr < 4; ++fr)
#pragma unroll
      for (int ks = 0; ks < 2; ++ks)
        a[fr][ks] = *(const short8*)&lA[buf][(size_t)(wr * 128 + rowoff + fr * 16 + lr) * 64 +
                                            (((ks * 4 + lh) ^ (lr & 7)) * 8)];
  };
  auto rdBlo = [&](int buf) {
#pragma unroll
    for (int fc = 0; fc < 2; ++fc)
#pragma unroll
      for (int ks = 0; ks < 2; ++ks)
        bl[fc][ks] = *(const short8*)&lB[buf][(size_t)(wc * 64 + fc * 16 + lr) * 64 +
                                              (((ks * 4 + lh) ^ (lr & 7)) * 8)];
  };
  auto rdBhi = [&](int buf) {
#pragma unroll
    for (int fc = 0; fc < 2; ++fc)
#pragma unroll
      for (int ks = 0; ks < 2; ++ks)
        bh[fc][ks] = *(const short8*)&lB[buf][(size_t)(wc * 64 + 32 + fc * 16 + lr) * 64 +
                                              (((ks * 4 + lh) ^ (lr & 7)) * 8)];
  };

#define MFMA_Q(FRO, FCO, BF)                                                        \
  do {                                                                              \
    __builtin_amdgcn_s_setprio(1);                                                  \
    _Pragma("unroll") for (int fr = 0; fr < 4; ++fr)                                \
    _Pragma("unroll") for (int fc = 0; fc < 2; ++fc)                                \
    _Pragma("unroll") for (int ks = 0; ks < 2; ++ks)                                \
        acc[(FRO) + fr][(FCO) + fc] = __builtin_amdgcn_mfma_f32_16x16x32_bf16(      \
            a[fr][ks], BF[fc][ks], acc[(FRO) + fr][(FCO) + fc], 0, 0, 0);           \
    __builtin_amdgcn_s_setprio(0);                                                  \
  } while (0)

#define BAR()                                \
  do {                                       \
    asm volatile("" ::: "memory");           \
    __builtin_amdgcn_s_barrier();            \
    asm volatile("" ::: "memory");           \
  } while (0)

  // prologue: tile0 -> buf0, tile1 -> buf1 (order mimics steady state)
  stageHalf(B, n0,       &lB[0][0],        0);
  stageHalf(A, m0,       &lA[0][0],        0);
  stageHalf(B, n0 + 128, &lB[0][128 * 64], 0);
  stageHalf(A, m0 + 128, &lA[0][128 * 64], 0);
  stageHalf(B, n0,       &lB[1][0],        64);
  stageHalf(B, n0 + 128, &lB[1][128 * 64], 64);
  stageHalf(A, m0,       &lA[1][0],        64);
  stageHalf(A, m0 + 128, &lA[1][128 * 64], 64);
  asm volatile("s_waitcnt vmcnt(8)" ::: "memory");   // tile0 landed (tile1 in flight)
  BAR();

  const int nk = K >> 6;
  const int nj = nk >> 1;

  for (int j = 0; j < nj; ++j) {
    const int k0e = (2 * j + 2) << 6;
    const int k0o = k0e + 64;
    const bool st = (2 * j + 2 < nk);

    // ========== even tile (buf 0) ==========
    // ph0: reads a-lo, b-lo; MFMA Q1
    rdA(0, 0); rdBlo(0);
    BAR();
    MFMA_Q(0, 0, bl);
    BAR();
    // ph1: reads b-hi; MFMA Q3
    rdBhi(0);
    BAR();
    MFMA_Q(0, 2, bh);
    BAR();
    // ph2: reads a-hi; stage Bh0(e); MFMA Q2
    rdA(0, 64);
    if (st) stageHalf(B, n0, &lB[0][0], k0e);
    BAR();
    MFMA_Q(4, 0, bl);
    BAR();
    // ph3: stage Ah0(e); MFMA Q4; counted wait for odd tile
    if (st) stageHalf(A, m0, &lA[0][0], k0e);
    BAR();
    MFMA_Q(4, 2, bh);
    if (st) asm volatile("s_waitcnt vmcnt(4)" ::: "memory");
    else    asm volatile("s_waitcnt vmcnt(0)" ::: "memory");
    BAR();

    // ========== odd tile (buf 1) ==========
    // ph4: reads a-lo, b-lo; stage Bh1(e); MFMA Q1
    rdA(1, 0); rdBlo(1);
    if (st) stageHalf(B, n0 + 128, &lB[0][128 * 64], k0e);
    BAR();
    MFMA_Q(0, 0, bl);
    BAR();
    // ph5: reads b-hi; stage Ah1(e); MFMA Q3
    rdBhi(1);
    if (st) stageHalf(A, m0 + 128, &lA[0][128 * 64], k0e);
    BAR();
    MFMA_Q(0, 2, bh);
    BAR();
    // ph6: reads a-hi; stage Bh0(o)+Bh1(o); MFMA Q2
    rdA(1, 64);
    if (st) { stageHalf(B, n0, &lB[1][0], k0o); stageHalf(B, n0 + 128, &lB[1][128 * 64], k0o); }
    BAR();
    MFMA_Q(4, 0, bl);
    BAR();
    // ph7: stage Ah0(o)+Ah1(o); MFMA Q4; counted wait for next even tile
    if (st) { stageHalf(A, m0, &lA[1][0], k0o); stageHalf(A, m0 + 128, &lA[1][128 * 64], k0o); }
    BAR();
    MFMA_Q(4, 2, bh);
    if (st) asm volatile("s_waitcnt vmcnt(8)" ::: "memory");
    BAR();
  }

#pragma unroll
  for (int fri = 0; fri < 8; ++fri)
#pragma unroll
    for (int fci = 0; fci < 4; ++fci)
#pragma unroll
      for (int r = 0; r < 4; ++r) {
        int row = m0 + wr * 128 + (fri >> 2) * 64 + (fri & 3) * 16 + lh * 4 + r;
        int col = n0 + wc * 64 + (fci >> 1) * 32 + (fci & 1) * 16 + lr;
        store_c(MODE, C, N, row, col, acc[fri][fci][r] + bias[col]);
      }
#undef MFMA_Q
#undef BAR
}

// ---------------------------------------------------------------- GEMM NT 128x128 (R8)
// single 32KB LDS, 2-barrier loop, residency hides latency; conflicts = 0.
template <int MODE, int NX>
__global__ __launch_bounds__(256, 4) void gemm_nt(const unsigned short* __restrict__ A,
                                                  const unsigned short* __restrict__ B,
                                                  const float* __restrict__ bias,
                                                  void* __restrict__ C,
                                                  int M, int N, int K) {
  __shared__ __align__(16) unsigned short lA[128 * 64];
  __shared__ __align__(16) unsigned short lB[128 * 64];
  const int tid = threadIdx.x;
  const int lane = tid & 63, wave = tid >> 6;
  const int lr = lane & 15, lh = lane >> 4;
  const int chunk = gridDim.x >> 3;
  const int g2 = (blockIdx.x & 7) * chunk + (blockIdx.x >> 3);
  const int m0 = (g2 / NX) * 128, n0 = (g2 % NX) * 128;
  const int wm = (wave >> 1) * 64, wn = (wave & 1) * 64;
  floatx4 acc[4][4] = {};

  for (int k0 = 0; k0 < K; k0 += 64) {
    __syncthreads();
#pragma unroll
    for (int c0 = 0; c0 < 1024; c0 += 256) {
      int L = c0 + tid;
      int r = L >> 3;
      int c = (L & 7) ^ (r & 7);
      async_copy16(A + (size_t)(m0 + r) * K + k0 + c * 8, &lA[(size_t)(c0 + wave * 64) * 8]);
      async_copy16(B + (size_t)(n0 + r) * K + k0 + c * 8, &lB[(size_t)(c0 + wave * 64) * 8]);
    }
    __syncthreads();
#pragma unroll
    for (int kk = 0; kk < 2; ++kk) {
      short8 af[4], bfr[4];
#pragma unroll
      for (int mf = 0; mf < 4; ++mf)
        af[mf] = *(const short8*)&lA[(wm + mf * 16 + lr) * 64 + (((kk * 4 + lh) ^ (lr & 7)) * 8)];
#pragma unroll
      for (int nf = 0; nf < 4; ++nf)
        bfr[nf] = *(const short8*)&lB[(wn + nf * 16 + lr) * 64 + (((kk * 4 + lh) ^ (lr & 7)) * 8)];
#pragma unroll
      for (int mf = 0; mf < 4; ++mf)
#pragma unroll
        for (int nf = 0; nf < 4; ++nf)
          acc[mf][nf] = __builtin_amdgcn_mfma_f32_16x16x32_bf16(af[mf], bfr[nf], acc[mf][nf], 0, 0, 0);
    }
  }

#pragma unroll
  for (int mf = 0; mf < 4; ++mf)
#pragma unroll
    for (int nf = 0; nf < 4; ++nf)
#pragma unroll
      for (int r = 0; r < 4; ++r) {
        int row = m0 + wm + mf * 16 + lh * 4 + r;
        int col = n0 + wn + nf * 16 + lr;
        store_c(MODE, C, N, row, col, acc[mf][nf][r] + bias[col]);
      }
}

// ---------------------------------------------------------------- attention
__global__ __launch_bounds__(256, 3) void attn_fwd(const unsigned short* __restrict__ Qb,
                                                   const unsigned short* __restrict__ Kb,
                                                   const unsigned short* __restrict__ Vt,
                                                   unsigned short* __restrict__ Att,
                                                   const int* __restrict__ causal_p) {
  __shared__ __align__(16) unsigned short lK[2][64 * 64];
  __shared__ __align__(16) unsigned short lV[2][64 * 64];
  __shared__ __align__(16) unsigned short lP[4][32 * 64];
  const int tid = threadIdx.x;
  const int lane = tid & 63, w = tid >> 6;
  const int lr = lane & 15, lh = lane >> 4;
  const int bid = blockIdx.x;
  const int g = (bid & 7) + 8 * (bid >> 7);
  int qt = (bid >> 3) & 15;
  qt = (qt & 12) | ((qt ^ (qt >> 2)) & 3);
  const int q0 = qt * 128;
  const int causal = causal_p[0];
  const size_t headOff = (size_t)g * 2048 * 64;
  const size_t vtHead = (size_t)g * 64 * 2048;
  const int q0w = q0 + w * 32;

  short8 qf[2][2];
#pragma unroll
  for (int qb = 0; qb < 2; ++qb)
#pragma unroll
    for (int kf = 0; kf < 2; ++kf)
      qf[qb][kf] = *(const short8*)&Qb[headOff + (size_t)(q0w + qb * 16 + lr) * 64 + kf * 32 + lh * 8];

  floatx4 oacc[2][4] = {};
  float mrow[2] = {-1e30f, -1e30f}, lrow[2] = {0.f, 0.f};

  const int nt = causal ? (q0 + 128) / 64 : 2048 / 64;
  const int qmax_w = q0w + 31;

  auto stageK = [&](int buf, int kv0) {
#pragma unroll
    for (int c0 = 0; c0 < 512; c0 += 256) {
      int L = c0 + tid;
      int kvr = L >> 3;
      int c = (tid & 7) ^ (kvr & 7);
      async_copy16(Kb + headOff + (size_t)(kv0 + kvr) * 64 + c * 8,
                   &lK[buf][(size_t)(c0 + w * 64) * 8]);
    }
  };
  auto stageV = [&](int buf, int kv0) {
#pragma unroll
    for (int c0 = 0; c0 < 512; c0 += 256) {
      int L = c0 + tid;
      int dr = L >> 3;
      int c = (tid & 7) ^ (dr & 7);
      async_copy16(Vt + vtHead + (size_t)dr * 2048 + kv0 + c * 8,
                   &lV[buf][(size_t)(c0 + w * 64) * 8]);
    }
  };

  stageK(0, 0);
  stageV(0, 0);
  int cur = 0;

  for (int t = 0; t < nt; ++t) {
    const int kv0 = t * 64;
    if (t + 1 < nt) {
      stageK(cur ^ 1, kv0 + 64);
      stageV(cur ^ 1, kv0 + 64);
      asm volatile("s_waitcnt vmcnt(4)" ::: "memory");
    } else {
      asm volatile("s_waitcnt vmcnt(0)" ::: "memory");
    }
    __builtin_amdgcn_s_barrier();
    asm volatile("" ::: "memory");

    if (!causal || kv0 <= qmax_w) {
      floatx4 sacc[2][4] = {};
      __builtin_amdgcn_s_setprio(1);
#pragma unroll
      for (int kk = 0; kk < 2; ++kk) {
        short8 kfr[4];
#pragma unroll
        for (int nf = 0; nf < 4; ++nf)
          kfr[nf] = *(const short8*)&lK[cur][(nf * 16 + lr) * 64 + (((kk * 4 + lh) ^ (lr & 7)) * 8)];
#pragma unroll
        for (int qb = 0; qb < 2; ++qb)
#pragma unroll
          for (int nf = 0; nf < 4; ++nf)
            sacc[qb][nf] = __builtin_amdgcn_mfma_f32_16x16x32_bf16(kfr[nf], qf[qb][kk], sacc[qb][nf], 0, 0, 0);
      }
      __builtin_amdgcn_s_setprio(0);

      if (causal && kv0 + 63 > q0w) {
#pragma unroll
        for (int qb = 0; qb < 2; ++qb) {
          int q = q0w + qb * 16 + lr;
#pragma unroll
          for (int nf = 0; nf < 4; ++nf)
#pragma unroll
            for (int r = 0; r < 4; ++r) {
              int kv = kv0 + nf * 16 + lh * 4 + r;
              if (kv > q) sacc[qb][nf][r] = -1e30f;
            }
        }
      }

      float alpha[2];
#pragma unroll
      for (int qb = 0; qb < 2; ++qb) {
        float rm = -1e30f;
#pragma unroll
        for (int nf = 0; nf < 4; ++nf)
          rm = fmaxf(rm, fmaxf(fmaxf(sacc[qb][nf][0], sacc[qb][nf][1]),
                               fmaxf(sacc[qb][nf][2], sacc[qb][nf][3])));
        rm = fmaxf(rm, __shfl_xor(rm, 16, 64));
        rm = fmaxf(rm, __shfl_xor(rm, 32, 64));
        float mn = fmaxf(mrow[qb], rm);
        alpha[qb] = fexp2(mrow[qb] - mn);
        mrow[qb] = mn;
        float rs = 0.f;
#pragma unroll
        for (int nf = 0; nf < 4; ++nf)
#pragma unroll
          for (int r = 0; r < 4; ++r) {
            float p = fexp2(sacc[qb][nf][r] - mn);
            sacc[qb][nf][r] = p;
            rs += p;
          }
        rs += __shfl_xor(rs, 16, 64);
        rs += __shfl_xor(rs, 32, 64);
        lrow[qb] = lrow[qb] * alpha[qb] + rs;
      }

#pragma unroll
      for (int qb = 0; qb < 2; ++qb)
#pragma unroll
        for (int nf = 0; nf < 4; ++nf) {
          uint2 pk;
          pk.x = cvt_pk_bf16(sacc[qb][nf][0], sacc[qb][nf][1]);
          pk.y = cvt_pk_bf16(sacc[qb][nf][2], sacc[qb][nf][3]);
          int c = (2 * nf + (lh >> 1)) ^ (lr & 7);
          *(uint2*)&lP[w][(qb * 16 + lr) * 64 + c * 8 + (lh & 1) * 4] = pk;
        }

#pragma unroll
      for (int qb = 0; qb < 2; ++qb) {
        float at[4];
#pragma unroll
        for (int r = 0; r < 4; ++r)
          at[r] = __shfl(alpha[qb], lh * 4 + r, 64);
#pragma unroll
        for (int nd = 0; nd < 4; ++nd)
#pragma unroll
          for (int r = 0; r < 4; ++r)
            oacc[qb][nd][r] *= at[r];
      }

      __builtin_amdgcn_s_setprio(1);
#pragma unroll
      for (int kk = 0; kk < 2; ++kk) {
        short8 pf[2], vf[4];
#pragma unroll
        for (int qb = 0; qb < 2; ++qb)
          pf[qb] = *(const short8*)&lP[w][(qb * 16 + lr) * 64 + (((kk * 4 + lh) ^ (lr & 7)) * 8)];
#pragma unroll
        for (int nd = 0; nd < 4; ++nd)
          vf[nd] = *(const short8*)&lV[cur][(nd * 16 + lr) * 64 + (((kk * 4 + lh) ^ (lr & 7)) * 8)];
#pragma unroll
        for (int qb = 0; qb < 2; ++qb)
#pragma unroll
          for (int nd = 0; nd < 4; ++nd)
            oacc[qb][nd] = __builtin_amdgcn_mfma_f32_16x16x32_bf16(pf[qb], vf[nd], oacc[qb][nd], 0, 0, 0);
      }
      __builtin_amdgcn_s_setprio(0);
    }
    asm volatile("" ::: "memory");
    __builtin_amdgcn_s_barrier();
    cur ^= 1;
  }

  const int bb = g >> 4, hh = g & 15;
#pragma unroll
  for (int qb = 0; qb < 2; ++qb) {
    float invl = 1.f / lrow[qb];
    float it[4];
#pragma unroll
    for (int r = 0; r < 4; ++r)
      it[r] = __shfl(invl, lh * 4 + r, 64);
#pragma unroll
    for (int r = 0; r < 4; ++r) {
      int s = q0w + qb * 16 + lh * 4 + r;
#pragma unroll
      for (int nd = 0; nd < 4; ++nd) {
        int dd = nd * 16 + lr;
        Att[((size_t)s * 4 + bb) * 1024 + hh * 64 + dd] = f2bf(oacc[qb][nd][r] * it[r]);
      }
    }
  }
}

// ---------------------------------------------------------------- launcher
extern "C" void kernel_launch(void* const* d_in, const int* in_sizes, int n_in,
                              void* d_out, int out_size, void* d_ws, size_t ws_size,
                              hipStream_t stream) {
  const float* x     = (const float*)d_in[0];
  const float* w_qkv = (const float*)d_in[1];
  const float* b_qkv = (const float*)d_in[2];
  const float* w_out = (const float*)d_in[3];
  const float* b_out = (const float*)d_in[4];
  const int*   causal = (const int*)d_in[5];
  float* out = (float*)d_out;

  char* ws = (char*)d_ws;
  size_t off = 0;
  auto alloc = [&](size_t bytes) { char* p = ws + off; off += (bytes + 255) & ~(size_t)255; return p; };
  unsigned short* Xbf  = (unsigned short*)alloc((size_t)8192 * 1024 * 2);
  unsigned short* Wqkv = (unsigned short*)alloc((size_t)3072 * 1024 * 2);
  unsigned short* Wout = (unsigned short*)alloc((size_t)1024 * 1024 * 2);
  unsigned short* QKV  = (unsigned short*)alloc((size_t)3 * 64 * 2048 * 64 * 2);
  unsigned short* Att  = (unsigned short*)alloc((size_t)8192 * 1024 * 2);
  (void)ws_size; (void)in_sizes; (void)n_in; (void)out_size;

  cvt_all<<<12288, 256, 0, stream>>>(x, w_qkv, w_out, Xbf, Wqkv, Wout);

  // QKV: 8-phase 256^2; grid 32x12 = 384 (div by 8 for XCD chunking)
  gemm256_8p<1, 12><<<384, 512, 0, stream>>>(Xbf, Wqkv, b_qkv, (void*)QKV, 8192, 3072, 1024);

  const unsigned short* Qh = QKV;
  const unsigned short* Kh = QKV + (size_t)64 * 2048 * 64;
  const unsigned short* Vh = QKV + (size_t)2 * 64 * 2048 * 64;
  attn_fwd<<<1024, 256, 0, stream>>>(Qh, Kh, Vh, Att, causal);

  gemm_nt<0, 8><<<8 * 64, 256, 0, stream>>>(Att, Wout, b_out, (void*)out, 8192, 1024, 1024);
}

// Round 11
// 176.217 us; speedup vs baseline: 1.2478x; 1.2409x over previous
//
#include <hip/hip_runtime.h>

typedef __attribute__((ext_vector_type(8))) short short8;
typedef __attribute__((ext_vector_type(4))) float floatx4;
typedef __attribute__((ext_vector_type(4))) unsigned short ushort4v;

__device__ __forceinline__ unsigned short f2bf(float f) {
  unsigned int u = __float_as_uint(f);
  u += 0x7FFFu + ((u >> 16) & 1u);           // round-to-nearest-even
  return (unsigned short)(u >> 16);
}

__device__ __forceinline__ unsigned int cvt_pk_bf16(float lo, float hi) {
  unsigned int r;
  asm("v_cvt_pk_bf16_f32 %0, %1, %2" : "=v"(r) : "v"(lo), "v"(hi));
  return r;
}

__device__ __forceinline__ void async_copy16(const void* g, void* l) {
  __builtin_amdgcn_global_load_lds(
      (const __attribute__((address_space(1))) unsigned int*)g,
      (__attribute__((address_space(3))) unsigned int*)l, 16, 0, 0);
}

__device__ __forceinline__ float fexp2(float x) {
#if __has_builtin(__builtin_amdgcn_exp2f)
  return __builtin_amdgcn_exp2f(x);
#else
  return exp2f(x);
#endif
}

// ---------------------------------------------------------------- convert (fused)
__global__ __launch_bounds__(256) void cvt_all(const float* __restrict__ x,
                                               const float* __restrict__ wq,
                                               const float* __restrict__ wo,
                                               unsigned short* __restrict__ Xb,
                                               unsigned short* __restrict__ Wqb,
                                               unsigned short* __restrict__ Wob) {
  int i = blockIdx.x * blockDim.x + threadIdx.x;
  const float* src;
  unsigned short* dst;
  int off;
  if (i < 2097152) { src = x;  dst = Xb;  off = i; }
  else if (i < 2883584) { src = wq; dst = Wqb; off = i - 2097152; }
  else { src = wo; dst = Wob; off = i - 2883584; }
  float4 v = reinterpret_cast<const float4*>(src)[off];
  ushort4v o;
  o[0] = f2bf(v.x); o[1] = f2bf(v.y); o[2] = f2bf(v.z); o[3] = f2bf(v.w);
  reinterpret_cast<ushort4v*>(dst)[off] = o;
}

// ---------------------------------------------------------------- GEMM NT 128x128
// R8 structure (best measured): single 32KB LDS, 2-barrier K-loop, 4 blocks/CU
// residency hides latency (m114), source-side XOR swizzle -> conflicts = 0,
// XCD-chunked 1D grid.
// NEW: MODE 1 part-2 (V) blocks do a block-local LDS transpose in the epilogue
// so Vt[g][d][s] stores are fully coalesced 64B lines (was: 2B scatter at 4KB
// stride = 64 lines per wave-store).
template <int MODE, int NX>
__global__ __launch_bounds__(256, 4) void gemm_nt(const unsigned short* __restrict__ A,
                                                  const unsigned short* __restrict__ B,
                                                  const float* __restrict__ bias,
                                                  void* __restrict__ C,
                                                  int M, int N, int K) {
  __shared__ __align__(16) unsigned short lds[2][128 * 64];
  unsigned short* lA = lds[0];
  unsigned short* lB = lds[1];
  unsigned short* lflat = &lds[0][0];
  const int tid = threadIdx.x;
  const int lane = tid & 63, wave = tid >> 6;
  const int lr = lane & 15, lh = lane >> 4;
  const int chunk = gridDim.x >> 3;
  const int g2 = (blockIdx.x & 7) * chunk + (blockIdx.x >> 3);
  const int m0 = (g2 / NX) * 128, n0 = (g2 % NX) * 128;
  const int wm = (wave >> 1) * 64, wn = (wave & 1) * 64;
  floatx4 acc[4][4] = {};

  for (int k0 = 0; k0 < K; k0 += 64) {
    __syncthreads();
#pragma unroll
    for (int c0 = 0; c0 < 1024; c0 += 256) {
      int L = c0 + tid;
      int r = L >> 3;
      int c = (L & 7) ^ (r & 7);
      async_copy16(A + (size_t)(m0 + r) * K + k0 + c * 8, &lA[(size_t)(c0 + wave * 64) * 8]);
      async_copy16(B + (size_t)(n0 + r) * K + k0 + c * 8, &lB[(size_t)(c0 + wave * 64) * 8]);
    }
    __syncthreads();
#pragma unroll
    for (int kk = 0; kk < 2; ++kk) {
      short8 af[4], bfr[4];
#pragma unroll
      for (int mf = 0; mf < 4; ++mf)
        af[mf] = *(const short8*)&lA[(wm + mf * 16 + lr) * 64 + (((kk * 4 + lh) ^ (lr & 7)) * 8)];
#pragma unroll
      for (int nf = 0; nf < 4; ++nf)
        bfr[nf] = *(const short8*)&lB[(wn + nf * 16 + lr) * 64 + (((kk * 4 + lh) ^ (lr & 7)) * 8)];
#pragma unroll
      for (int mf = 0; mf < 4; ++mf)
#pragma unroll
        for (int nf = 0; nf < 4; ++nf)
          acc[mf][nf] = __builtin_amdgcn_mfma_f32_16x16x32_bf16(af[mf], bfr[nf], acc[mf][nf], 0, 0, 0);
    }
  }

  if (MODE == 1 && (n0 >> 10) == 2) {
    // ---- V part: LDS-transposed coalesced store path ----
    // thread value (mf,nf,r): local row = wm+mf*16+lh*4+r -> b=r, s_local =
    // wm/4+mf*4+lh; local col cl = wn+nf*16+lr -> hh=cl>>6, dd=cl&63.
    // LDS layout: idx = ((b*2+hh)*64+dd)*32 + (s_local ^ ((dd&3)<<3)).
    __syncthreads();   // all waves done with final K-step LDS reads
#pragma unroll
    for (int mf = 0; mf < 4; ++mf) {
      int sl = (wm >> 2) + mf * 4 + lh;
#pragma unroll
      for (int nf = 0; nf < 4; ++nf) {
        int cl = wn + nf * 16 + lr;
        int hh = cl >> 6, dd = cl & 63;
        int sx = sl ^ ((dd & 3) << 3);
#pragma unroll
        for (int r = 0; r < 4; ++r) {
          float v = acc[mf][nf][r] + bias[n0 + cl];
          lflat[((r * 2 + hh) * 64 + dd) * 32 + sx] = f2bf(v);
        }
      }
    }
    __syncthreads();
    // readback: flat f = tid + k*256 in 0..2047; p=f>>2 (pair: b,hh,dd), q=f&3
    // (16B chunk). 4 consecutive lanes = one fully-written 64B line.
    const int hbase = (n0 & 1023) >> 6;
    const int s0g = m0 >> 2;
    unsigned short* V = (unsigned short*)C + (size_t)2 * 64 * 2048 * 64;
#pragma unroll
    for (int k = 0; k < 8; ++k) {
      int f = tid + k * 256;
      int p = f >> 2, q = f & 3;
      int b = p >> 7, hh = (p >> 6) & 1, dd = p & 63;
      int g = b * 16 + hbase + hh;
      int sc = (q ^ (dd & 3)) * 8;
      short8 vv = *(const short8*)&lflat[p * 32 + q * 8];
      *(short8*)&V[((size_t)g * 64 + dd) * 2048 + s0g + sc] = vv;
    }
  } else {
#pragma unroll
    for (int mf = 0; mf < 4; ++mf)
#pragma unroll
      for (int nf = 0; nf < 4; ++nf)
#pragma unroll
        for (int r = 0; r < 4; ++r) {
          int row = m0 + wm + mf * 16 + lh * 4 + r;
          int col = n0 + wn + nf * 16 + lr;
          float v = acc[mf][nf][r] + bias[col];
          if (MODE == 0) {
            ((float*)C)[(size_t)row * N + col] = v;
          } else {
            // part 0 (Q, scaled) or part 1 (K): coalesced-ish bf16 stores
            int part = col >> 10, wi = col & 1023;
            int h = wi >> 6, dd = wi & 63;
            int s = row >> 2, b = row & 3;
            int gg = b * 16 + h;
            size_t base = (size_t)part * (64u * 2048u * 64u);
            if (part == 0) v *= 0.18033688011112042f;  // 1/sqrt(d_k)*log2(e)
            ((unsigned short*)C)[base + ((size_t)gg * 2048 + s) * 64 + dd] = f2bf(v);
          }
        }
  }
}

// ---------------------------------------------------------------- attention
// 1024 blocks (XCD-swizzled; qt remapped for per-CU causal balance).
// 4 waves x 32 q-rows, KV tile 64, dbuf pipelined staging, swapped QK^T.
__global__ __launch_bounds__(256, 3) void attn_fwd(const unsigned short* __restrict__ Qb,
                                                   const unsigned short* __restrict__ Kb,
                                                   const unsigned short* __restrict__ Vt,
                                                   unsigned short* __restrict__ Att,
                                                   const int* __restrict__ causal_p) {
  __shared__ __align__(16) unsigned short lK[2][64 * 64];
  __shared__ __align__(16) unsigned short lV[2][64 * 64];
  __shared__ __align__(16) unsigned short lP[4][32 * 64];
  const int tid = threadIdx.x;
  const int lane = tid & 63, w = tid >> 6;
  const int lr = lane & 15, lh = lane >> 4;
  const int bid = blockIdx.x;
  const int g = (bid & 7) + 8 * (bid >> 7);
  int qt = (bid >> 3) & 15;
  qt = (qt & 12) | ((qt ^ (qt >> 2)) & 3);
  const int q0 = qt * 128;
  const int causal = causal_p[0];
  const size_t headOff = (size_t)g * 2048 * 64;
  const size_t vtHead = (size_t)g * 64 * 2048;
  const int q0w = q0 + w * 32;

  short8 qf[2][2];
#pragma unroll
  for (int qb = 0; qb < 2; ++qb)
#pragma unroll
    for (int kf = 0; kf < 2; ++kf)
      qf[qb][kf] = *(const short8*)&Qb[headOff + (size_t)(q0w + qb * 16 + lr) * 64 + kf * 32 + lh * 8];

  floatx4 oacc[2][4] = {};
  float mrow[2] = {-1e30f, -1e30f}, lrow[2] = {0.f, 0.f};

  const int nt = causal ? (q0 + 128) / 64 : 2048 / 64;
  const int qmax_w = q0w + 31;

  auto stageK = [&](int buf, int kv0) {
#pragma unroll
    for (int c0 = 0; c0 < 512; c0 += 256) {
      int L = c0 + tid;
      int kvr = L >> 3;
      int c = (tid & 7) ^ (kvr & 7);
      async_copy16(Kb + headOff + (size_t)(kv0 + kvr) * 64 + c * 8,
                   &lK[buf][(size_t)(c0 + w * 64) * 8]);
    }
  };
  auto stageV = [&](int buf, int kv0) {
#pragma unroll
    for (int c0 = 0; c0 < 512; c0 += 256) {
      int L = c0 + tid;
      int dr = L >> 3;
      int c = (tid & 7) ^ (dr & 7);
      async_copy16(Vt + vtHead + (size_t)dr * 2048 + kv0 + c * 8,
                   &lV[buf][(size_t)(c0 + w * 64) * 8]);
    }
  };

  stageK(0, 0);
  stageV(0, 0);
  int cur = 0;

  for (int t = 0; t < nt; ++t) {
    const int kv0 = t * 64;
    if (t + 1 < nt) {
      stageK(cur ^ 1, kv0 + 64);
      stageV(cur ^ 1, kv0 + 64);
      asm volatile("s_waitcnt vmcnt(4)" ::: "memory");
    } else {
      asm volatile("s_waitcnt vmcnt(0)" ::: "memory");
    }
    __builtin_amdgcn_s_barrier();
    asm volatile("" ::: "memory");

    if (!causal || kv0 <= qmax_w) {
      floatx4 sacc[2][4] = {};
      __builtin_amdgcn_s_setprio(1);
#pragma unroll
      for (int kk = 0; kk < 2; ++kk) {
        short8 kfr[4];
#pragma unroll
        for (int nf = 0; nf < 4; ++nf)
          kfr[nf] = *(const short8*)&lK[cur][(nf * 16 + lr) * 64 + (((kk * 4 + lh) ^ (lr & 7)) * 8)];
#pragma unroll
        for (int qb = 0; qb < 2; ++qb)
#pragma unroll
          for (int nf = 0; nf < 4; ++nf)
            sacc[qb][nf] = __builtin_amdgcn_mfma_f32_16x16x32_bf16(kfr[nf], qf[qb][kk], sacc[qb][nf], 0, 0, 0);
      }
      __builtin_amdgcn_s_setprio(0);

      if (causal && kv0 + 63 > q0w) {
#pragma unroll
        for (int qb = 0; qb < 2; ++qb) {
          int q = q0w + qb * 16 + lr;
#pragma unroll
          for (int nf = 0; nf < 4; ++nf)
#pragma unroll
            for (int r = 0; r < 4; ++r) {
              int kv = kv0 + nf * 16 + lh * 4 + r;
              if (kv > q) sacc[qb][nf][r] = -1e30f;
            }
        }
      }

      float alpha[2];
#pragma unroll
      for (int qb = 0; qb < 2; ++qb) {
        float rm = -1e30f;
#pragma unroll
        for (int nf = 0; nf < 4; ++nf)
          rm = fmaxf(rm, fmaxf(fmaxf(sacc[qb][nf][0], sacc[qb][nf][1]),
                               fmaxf(sacc[qb][nf][2], sacc[qb][nf][3])));
        rm = fmaxf(rm, __shfl_xor(rm, 16, 64));
        rm = fmaxf(rm, __shfl_xor(rm, 32, 64));
        float mn = fmaxf(mrow[qb], rm);
        alpha[qb] = fexp2(mrow[qb] - mn);
        mrow[qb] = mn;
        float rs = 0.f;
#pragma unroll
        for (int nf = 0; nf < 4; ++nf)
#pragma unroll
          for (int r = 0; r < 4; ++r) {
            float p = fexp2(sacc[qb][nf][r] - mn);
            sacc[qb][nf][r] = p;
            rs += p;
          }
        rs += __shfl_xor(rs, 16, 64);
        rs += __shfl_xor(rs, 32, 64);
        lrow[qb] = lrow[qb] * alpha[qb] + rs;
      }

#pragma unroll
      for (int qb = 0; qb < 2; ++qb)
#pragma unroll
        for (int nf = 0; nf < 4; ++nf) {
          uint2 pk;
          pk.x = cvt_pk_bf16(sacc[qb][nf][0], sacc[qb][nf][1]);
          pk.y = cvt_pk_bf16(sacc[qb][nf][2], sacc[qb][nf][3]);
          int c = (2 * nf + (lh >> 1)) ^ (lr & 7);
          *(uint2*)&lP[w][(qb * 16 + lr) * 64 + c * 8 + (lh & 1) * 4] = pk;
        }

#pragma unroll
      for (int qb = 0; qb < 2; ++qb) {
        float at[4];
#pragma unroll
        for (int r = 0; r < 4; ++r)
          at[r] = __shfl(alpha[qb], lh * 4 + r, 64);
#pragma unroll
        for (int nd = 0; nd < 4; ++nd)
#pragma unroll
          for (int r = 0; r < 4; ++r)
            oacc[qb][nd][r] *= at[r];
      }

      __builtin_amdgcn_s_setprio(1);
#pragma unroll
      for (int kk = 0; kk < 2; ++kk) {
        short8 pf[2], vf[4];
#pragma unroll
        for (int qb = 0; qb < 2; ++qb)
          pf[qb] = *(const short8*)&lP[w][(qb * 16 + lr) * 64 + (((kk * 4 + lh) ^ (lr & 7)) * 8)];
#pragma unroll
        for (int nd = 0; nd < 4; ++nd)
          vf[nd] = *(const short8*)&lV[cur][(nd * 16 + lr) * 64 + (((kk * 4 + lh) ^ (lr & 7)) * 8)];
#pragma unroll
        for (int qb = 0; qb < 2; ++qb)
#pragma unroll
          for (int nd = 0; nd < 4; ++nd)
            oacc[qb][nd] = __builtin_amdgcn_mfma_f32_16x16x32_bf16(pf[qb], vf[nd], oacc[qb][nd], 0, 0, 0);
      }
      __builtin_amdgcn_s_setprio(0);
    }
    asm volatile("" ::: "memory");
    __builtin_amdgcn_s_barrier();
    cur ^= 1;
  }

  const int bb = g >> 4, hh = g & 15;
#pragma unroll
  for (int qb = 0; qb < 2; ++qb) {
    float invl = 1.f / lrow[qb];
    float it[4];
#pragma unroll
    for (int r = 0; r < 4; ++r)
      it[r] = __shfl(invl, lh * 4 + r, 64);
#pragma unroll
    for (int r = 0; r < 4; ++r) {
      int s = q0w + qb * 16 + lh * 4 + r;
#pragma unroll
      for (int nd = 0; nd < 4; ++nd) {
        int dd = nd * 16 + lr;
        Att[((size_t)s * 4 + bb) * 1024 + hh * 64 + dd] = f2bf(oacc[qb][nd][r] * it[r]);
      }
    }
  }
}

// ---------------------------------------------------------------- launcher
extern "C" void kernel_launch(void* const* d_in, const int* in_sizes, int n_in,
                              void* d_out, int out_size, void* d_ws, size_t ws_size,
                              hipStream_t stream) {
  const float* x     = (const float*)d_in[0];
  const float* w_qkv = (const float*)d_in[1];
  const float* b_qkv = (const float*)d_in[2];
  const float* w_out = (const float*)d_in[3];
  const float* b_out = (const float*)d_in[4];
  const int*   causal = (const int*)d_in[5];
  float* out = (float*)d_out;

  char* ws = (char*)d_ws;
  size_t off = 0;
  auto alloc = [&](size_t bytes) { char* p = ws + off; off += (bytes + 255) & ~(size_t)255; return p; };
  unsigned short* Xbf  = (unsigned short*)alloc((size_t)8192 * 1024 * 2);
  unsigned short* Wqkv = (unsigned short*)alloc((size_t)3072 * 1024 * 2);
  unsigned short* Wout = (unsigned short*)alloc((size_t)1024 * 1024 * 2);
  unsigned short* QKV  = (unsigned short*)alloc((size_t)3 * 64 * 2048 * 64 * 2);
  unsigned short* Att  = (unsigned short*)alloc((size_t)8192 * 1024 * 2);
  (void)ws_size; (void)in_sizes; (void)n_in; (void)out_size;

  cvt_all<<<12288, 256, 0, stream>>>(x, w_qkv, w_out, Xbf, Wqkv, Wout);

  // 1D grids, XCD-chunked decode inside; nwg divisible by 8
  gemm_nt<1, 24><<<24 * 64, 256, 0, stream>>>(Xbf, Wqkv, b_qkv, (void*)QKV, 8192, 3072, 1024);

  const unsigned short* Qh = QKV;
  const unsigned short* Kh = QKV + (size_t)64 * 2048 * 64;
  const unsigned short* Vh = QKV + (size_t)2 * 64 * 2048 * 64;
  attn_fwd<<<1024, 256, 0, stream>>>(Qh, Kh, Vh, Att, causal);

  gemm_nt<0, 8><<<8 * 64, 256, 0, stream>>>(Att, Wout, b_out, (void*)out, 8192, 1024, 1024);
}